// Round 14
// baseline (9714.101 us; speedup 1.0000x reference)
//
#include <hip/hip_runtime.h>
#include <hip/hip_bf16.h>

#define NB   32
#define HH   1024
#define LL   512
#define KTOT 2048

typedef __bf16 bf8 __attribute__((ext_vector_type(8)));
typedef float  f4  __attribute__((ext_vector_type(4)));
typedef unsigned short us8 __attribute__((ext_vector_type(8)));

// Software round-to-nearest-even f32 -> bf16 (R1/R5/R8/R9-proven numerics)
__device__ __forceinline__ unsigned short f2bf(float f) {
  unsigned u = __builtin_bit_cast(unsigned, f);
  u += 0x7fffu + ((u >> 16) & 1u);
  return (unsigned short)(u >> 16);
}
__device__ __forceinline__ us8 pack8(f4 a, f4 b) {
  us8 r;
  r[0]=f2bf(a[0]); r[1]=f2bf(a[1]); r[2]=f2bf(a[2]); r[3]=f2bf(a[3]);
  r[4]=f2bf(b[0]); r[5]=f2bf(b[1]); r[6]=f2bf(b[2]); r[7]=f2bf(b[3]);
  return r;
}

// NEW consumer wait (the one untested clean combination):
//   lanes 0..7 RELAXED-poll their 64B sub-counter line (sc1 read at the
//   coherence point -> always fresh, NO buffer_inv per poll),
//   barrier, then ONE acquire fence per wave (single L1+L2 invalidate after
//   the flag is known set) -> plain coalesced loads are stale-proof.
// R9's acquire-spin emitted an inv EVERY poll (~every 500ns per waiting WG,
// 16 WGs/XCD -> continuous L2 wipe). R13 proved relaxed polls are sound;
// R2/R3/R4's zeros were stale-clean poison lines (no inv at all), R6/R7's
// were >256-VGPR launch rejection — neither refutes this recipe.
__device__ __forceinline__ void waitsubs(unsigned* base, unsigned tgt) {
  if (threadIdx.x < 8) {
    unsigned* p = base + threadIdx.x * 16;        // 16 dwords = 64B stride
    while (__hip_atomic_load(p, __ATOMIC_RELAXED, __HIP_MEMORY_SCOPE_AGENT) < tgt)
      __builtin_amdgcn_s_sleep(8);
  }
  __syncthreads();
  __builtin_amdgcn_fence(__ATOMIC_ACQUIRE, "agent");   // one inv, then fresh loads
}

// Write-through data store (R9-proven): lands at coherence point.
__device__ __forceinline__ void stwt(unsigned* p, unsigned v) {
  __hip_atomic_store(p, v, __ATOMIC_RELAXED, __HIP_MEMORY_SCOPE_AGENT);
}

// ---- optional pre-pass (only if ws_size allows): x0[t][n][h] = bf16(emb[tokens]) ----
__global__ void __launch_bounds__(256)
prepack(const int* __restrict__ tokens, const float* __restrict__ emb,
        unsigned short* __restrict__ x0) {
  int idx = blockIdx.x * 256 + threadIdx.x;     // 32*512*128 = 2,097,152
  int n  = idx >> 16;
  int t  = (idx >> 7) & 511;
  int h  = (idx & 127) << 3;
  int row = tokens[n * LL + t];
  const float* src = emb + (size_t)row * HH + h;
  *(us8*)(x0 + ((size_t)t * NB + n) * HH + h) = pack8(*(const f4*)src, *(const f4*)(src + 4));
}

// ---- persistent dataflow LSTM: 256 WGs x 256 thr (R9 geometry). WG w:
// layer=w>>7, h-octet w&127. Producer (unchanged): write-through stores ->
// __syncthreads (vmcnt drained: data at MALL) -> tid0 RELEASE fetch_add on
// sub-counter (wg&7). Consumer: waitsubs (relaxed poll + single fence) ->
// plain coalesced loads.
__global__ void __launch_bounds__(256, 1)
lstm_persist(const int* __restrict__ tokens, const float* __restrict__ emb,
             const float* __restrict__ W, const float* __restrict__ Bb,
             float* __restrict__ out, unsigned* flags, unsigned short* s1,
             unsigned short* s2, const unsigned short* x0)
{
  // wlds fragment order: slot(jh, cm, lane) = jh*4096 + cm*64 + lane (8 bf16 each):
  // W row j = jh*16+(lane&15), k = cm*32 + (lane>>4)*8 .. +8 -> lane-linear ds_read_b128
  __shared__ unsigned short wlds[65536];   // 128 KiB
  __shared__ float glds[32 * 36];
  __shared__ float bias[32];

  const int tid   = threadIdx.x;
  const int layer = blockIdx.x >> 7;
  const int wg    = blockIdx.x & 127;
  const int h0    = wg * 8;
  // sub-counter layout (R9): cnt[layer][t][sub], sub-stride 16 dwords (64B line)
  unsigned* cnt1  = flags;                  // layer-0: 512 steps x 8 subs x 16
  unsigned* cnt2  = flags + 512 * 128;      // layer-1
  unsigned* mycnt = layer ? cnt2 : cnt1;
  const int mysub = (wg & 7) * 16;

  // one-time: W slice (32 rows x 2048 f32, coalesced) -> fragment-ordered bf16 LDS
  for (int it = 0; it < 32; ++it) {
    int e = (it * 256 + tid) * 8;
    int r = e >> 11;                       // local row: gate = r>>3, i = r&7
    int k = e & 2047;
    const float* src = W + (((size_t)layer * 4 + (r >> 3)) * HH + (h0 + (r & 7))) * (size_t)KTOT + k;
    int slot = ((r >> 4) << 12) + (((k >> 8) * 8 + ((k >> 5) & 7)) << 6) + (r & 15) + (((k >> 3) & 3) << 4);
    *(us8*)&wlds[(unsigned)slot * 8] = pack8(*(const f4*)src, *(const f4*)(src + 4));
  }
  if (tid < 32) bias[tid] = Bb[((size_t)layer * 4 + (tid >> 3)) * HH + h0 + (tid & 7)];
  __syncthreads();

  const int lane = tid & 63;
  const int wid  = tid >> 6;
  const int nh = wid >> 1, jh = wid & 1;
  const int arow  = nh * 16 + (lane & 15);     // batch row for A fragments
  const int rbase = (lane >> 4) * 8;           // k-slice within 32-wide K step
  const unsigned short* wbase = &wlds[((unsigned)(jh * 4096 + lane)) * 8u];

  float lng = 0.f;                             // cell state (n=tid>>3, h=h0+(tid&7))

  for (int t = 0; t < LL; ++t) {
    us8 nf[4][8], rf[4][8];
    f4 acc = {0.f, 0.f, 0.f, 0.f};

    // ---------- "now" half (flag-free for layer 0; cnt1[t] for layer 1) ----------
    if (layer == 0) {
      if (x0) {
        const unsigned short* nsrc = x0 + ((size_t)t * NB + arow) * HH + rbase;
        #pragma unroll
        for (int c = 0; c < 4; ++c)
          #pragma unroll
          for (int m = 0; m < 8; ++m)
            nf[c][m] = *(const us8*)(nsrc + c * 256 + m * 32);
      } else {
        const float* nsrc = emb + (size_t)tokens[arow * LL + t] * HH + rbase;
        #pragma unroll
        for (int c = 0; c < 4; ++c)
          #pragma unroll
          for (int m = 0; m < 8; ++m)
            nf[c][m] = pack8(*(const f4*)(nsrc + c * 256 + m * 32),
                             *(const f4*)(nsrc + c * 256 + m * 32 + 4));
      }
    } else {
      waitsubs(cnt1 + (size_t)t * 128, 16);
      const unsigned short* nsrc = s1 + ((size_t)t * NB + arow) * HH + rbase;
      #pragma unroll
      for (int c = 0; c < 4; ++c)
        #pragma unroll
        for (int m = 0; m < 8; ++m)
          nf[c][m] = *(const us8*)(nsrc + c * 256 + m * 32);
    }
    #pragma unroll
    for (int c = 0; c < 4; ++c)
      #pragma unroll
      for (int m = 0; m < 8; ++m)
        acc = __builtin_amdgcn_mfma_f32_16x16x32_bf16(
                __builtin_bit_cast(bf8, nf[c][m]),
                __builtin_bit_cast(bf8, *(const us8*)(wbase + ((4 + c) * 8 + m) * 512)),
                acc, 0, 0, 0);

    // ---------- recurrent half (own layer's previous step) ----------
    if (t > 0) {
      waitsubs(mycnt + (size_t)(t - 1) * 128, 16);
      if (layer == 0) {
        const unsigned short* rsrc = s1 + ((size_t)(t - 1) * NB + arow) * HH + rbase;
        #pragma unroll
        for (int c = 0; c < 4; ++c)
          #pragma unroll
          for (int m = 0; m < 8; ++m)
            rf[c][m] = *(const us8*)(rsrc + c * 256 + m * 32);
      } else if (s2) {
        const unsigned short* rsrc = s2 + ((size_t)(t - 1) * NB + arow) * HH + rbase;
        #pragma unroll
        for (int c = 0; c < 4; ++c)
          #pragma unroll
          for (int m = 0; m < 8; ++m)
            rf[c][m] = *(const us8*)(rsrc + c * 256 + m * 32);
      } else {
        const float* rsrc = out + ((size_t)arow * LL + (t - 1)) * HH + rbase;
        #pragma unroll
        for (int c = 0; c < 4; ++c)
          #pragma unroll
          for (int m = 0; m < 8; ++m)
            rf[c][m] = pack8(*(const f4*)(rsrc + c * 256 + m * 32),
                             *(const f4*)(rsrc + c * 256 + m * 32 + 4));
      }
      #pragma unroll
      for (int c = 0; c < 4; ++c)
        #pragma unroll
        for (int m = 0; m < 8; ++m)
          acc = __builtin_amdgcn_mfma_f32_16x16x32_bf16(
                  __builtin_bit_cast(bf8, rf[c][m]),
                  __builtin_bit_cast(bf8, *(const us8*)(wbase + (c * 8 + m) * 512)),
                  acc, 0, 0, 0);
    }

    // ---------- scatter gates (C/D: col=lane&15, row=(lane>>4)*4+reg) ----------
    {
      int grow = nh * 16 + ((lane >> 4) << 2);
      int gcol = jh * 16 + (lane & 15);
      glds[(grow + 0) * 36 + gcol] = acc[0];
      glds[(grow + 1) * 36 + gcol] = acc[1];
      glds[(grow + 2) * 36 + gcol] = acc[2];
      glds[(grow + 3) * 36 + gcol] = acc[3];
    }
    __syncthreads();

    // ---------- state update: thread owns (n=tid>>3, i=tid&7); gates f,i,o,cand ----------
    {
      int n = tid >> 3, i = tid & 7;
      float gf = glds[n * 36 +  0 + i] + bias[ 0 + i];
      float gi = glds[n * 36 +  8 + i] + bias[ 8 + i];
      float go = glds[n * 36 + 16 + i] + bias[16 + i];
      float gc = glds[n * 36 + 24 + i] + bias[24 + i];
      float fg = 1.f / (1.f + __expf(-gf));
      float ig = 1.f / (1.f + __expf(-gi));
      float og = 1.f / (1.f + __expf(-go));
      lng = fg * lng + ig * gc;                     // cand raw (matches reference)
      float a  = fabsf(lng);
      float e  = __expf(-2.f * a);
      float th = __builtin_copysignf((1.f - e) / (1.f + e), lng);
      float sh = og * th;

      unsigned v16 = f2bf(sh);
      unsigned nb  = __shfl_down(v16, 1);
      unsigned pair = v16 | (nb << 16);

      if (layer == 0) {
        if (!(i & 1))
          stwt((unsigned*)(s1 + ((size_t)t * NB + n) * HH + h0 + i), pair);
      } else {
        stwt((unsigned*)(out + ((size_t)n * LL + t) * HH + h0 + i),
             __builtin_bit_cast(unsigned, sh));
        if (s2 && !(i & 1))
          stwt((unsigned*)(s2 + ((size_t)t * NB + n) * HH + h0 + i), pair);
      }
    }
    __syncthreads();   // vmcnt(0) per wave: all write-through stores at MALL
    if (tid == 0)
      __hip_atomic_fetch_add(mycnt + (size_t)t * 128 + mysub, 1u,
                             __ATOMIC_RELEASE, __HIP_MEMORY_SCOPE_AGENT);
  }
}

extern "C" void kernel_launch(void* const* d_in, const int* in_sizes, int n_in,
                              void* d_out, int out_size, void* d_ws, size_t ws_size,
                              hipStream_t stream) {
  const int*   tokens = (const int*)d_in[0];
  const float* emb    = (const float*)d_in[1];
  const float* W      = (const float*)d_in[2];
  const float* Bb     = (const float*)d_in[3];
  float*       out    = (float*)d_out;

  // ws layout (R9):
  //   [0, 512KB)    sub-counters: cnt[2][512][8] on separate 64B lines
  //   [512KB,+32MB) s1 bf16 [512][32][1024]                    (required)
  //   optional s2 (layer-1 bf16 state), optional x0 (prepacked emb)
  const size_t FL = 524288;
  const size_t SZ = (size_t)LL * NB * HH * sizeof(unsigned short);   // 32 MiB
  unsigned*       flags = (unsigned*)d_ws;
  unsigned short* s1    = (unsigned short*)((char*)d_ws + FL);
  unsigned short* s2    = (ws_size >= FL + 2 * SZ) ? (unsigned short*)((char*)d_ws + FL + SZ) : nullptr;
  unsigned short* x0    = (ws_size >= FL + 3 * SZ) ? (unsigned short*)((char*)d_ws + FL + 2 * SZ) : nullptr;

  hipMemsetAsync(d_ws, 0, FL, stream);   // zero counters every replay (graph-captured)
  if (x0) prepack<<<dim3(8192), dim3(256), 0, stream>>>(tokens, emb, x0);

  void* args[] = { (void*)&tokens, (void*)&emb, (void*)&W, (void*)&Bb,
                   (void*)&out, (void*)&flags, (void*)&s1, (void*)&s2, (void*)&x0 };
  hipLaunchCooperativeKernel((void*)lstm_persist, dim3(256), dim3(256), args, 0, stream);
}

// Round 15
// 7546.426 us; speedup vs baseline: 1.2872x; 1.2872x over previous
//
#include <hip/hip_runtime.h>
#include <hip/hip_bf16.h>

#define NB   32
#define HH   1024
#define LL   512
#define KTOT 2048

typedef __bf16 bf8 __attribute__((ext_vector_type(8)));
typedef float  f4  __attribute__((ext_vector_type(4)));
typedef unsigned short us8 __attribute__((ext_vector_type(8)));

#define MFMA(a, b, c) __builtin_amdgcn_mfma_f32_16x16x32_bf16( \
    __builtin_bit_cast(bf8, a), __builtin_bit_cast(bf8, b), c, 0, 0, 0)

// Software round-to-nearest-even f32 -> bf16 (R1/R5/R8/R9-proven numerics)
__device__ __forceinline__ unsigned short f2bf(float f) {
  unsigned u = __builtin_bit_cast(unsigned, f);
  u += 0x7fffu + ((u >> 16) & 1u);
  return (unsigned short)(u >> 16);
}
__device__ __forceinline__ us8 pack8(f4 a, f4 b) {
  us8 r;
  r[0]=f2bf(a[0]); r[1]=f2bf(a[1]); r[2]=f2bf(a[2]); r[3]=f2bf(a[3]);
  r[4]=f2bf(b[0]); r[5]=f2bf(b[1]); r[6]=f2bf(b[2]); r[7]=f2bf(b[3]);
  return r;
}

// FROZEN sync primitive (R9 exact — best-measured; R12/R13/R14 variants all
// regressed): lanes 0..7 ACQUIRE-spin on their own 64B sub-counter line,
// then block barrier; plain coalesced data loads after.
__device__ __forceinline__ void waitsubs(unsigned* base, unsigned tgt) {
  if (threadIdx.x < 8) {
    unsigned* p = base + threadIdx.x * 16;        // 16 dwords = 64B stride
    while (__hip_atomic_load(p, __ATOMIC_ACQUIRE, __HIP_MEMORY_SCOPE_AGENT) < tgt)
      __builtin_amdgcn_s_sleep(8);
  }
  __syncthreads();
}
// Write-through data store (R9-proven): lands at coherence point.
__device__ __forceinline__ void stwt(unsigned* p, unsigned v) {
  __hip_atomic_store(p, v, __ATOMIC_RELAXED, __HIP_MEMORY_SCOPE_AGENT);
}

// ---- optional pre-pass (only if ws_size allows): x0[t][n][h] = bf16(emb[tokens]) ----
__global__ void __launch_bounds__(256)
prepack(const int* __restrict__ tokens, const float* __restrict__ emb,
        unsigned short* __restrict__ x0) {
  int idx = blockIdx.x * 256 + threadIdx.x;     // 32*512*128 = 2,097,152
  int n  = idx >> 16;
  int t  = (idx >> 7) & 511;
  int h  = (idx & 127) << 3;
  int row = tokens[n * LL + t];
  const float* src = emb + (size_t)row * HH + h;
  *(us8*)(x0 + ((size_t)t * NB + n) * HH + h) = pack8(*(const f4*)src, *(const f4*)(src + 4));
}

// ---- persistent dataflow LSTM: 256 WGs x 256 thr (R9 geometry + sync).
// NEW schedule: each layer's flag-free/self-layer half runs AFTER its release,
// inside the wait window, carrying only acc (16B) across the wait:
//   layer 0 chain: discover(cnt1[t-1]) -> rf -> epilogue    (nf(t+1) off-chain)
//   layer 1 chain: discover(cnt1[t])   -> nf -> epilogue    (rf(t+1) off-chain,
//                  gated by cnt2[t] which peers released one period earlier)
__global__ void __launch_bounds__(256, 1)
lstm_persist(const int* __restrict__ tokens, const float* __restrict__ emb,
             const float* __restrict__ W, const float* __restrict__ Bb,
             float* __restrict__ out, unsigned* flags, unsigned short* s1,
             unsigned short* s2, const unsigned short* x0)
{
  // wlds fragment order: slot(jh, cm, lane) = jh*4096 + cm*64 + lane (8 bf16 each):
  // W row j = jh*16+(lane&15), k = cm*32 + (lane>>4)*8 .. +8 -> lane-linear ds_read_b128
  __shared__ unsigned short wlds[65536];   // 128 KiB
  __shared__ float glds[32 * 36];
  __shared__ float bias[32];

  const int tid   = threadIdx.x;
  const int layer = blockIdx.x >> 7;
  const int wg    = blockIdx.x & 127;
  const int h0    = wg * 8;
  // sub-counter layout (R9): cnt[layer][t][sub], sub-stride 16 dwords (64B line)
  unsigned* cnt1  = flags;                  // layer-0: 512 steps x 8 subs x 16
  unsigned* cnt2  = flags + 512 * 128;      // layer-1
  unsigned* mycnt = layer ? cnt2 : cnt1;
  const int mysub = (wg & 7) * 16;

  // one-time: W slice (32 rows x 2048 f32, coalesced) -> fragment-ordered bf16 LDS
  for (int it = 0; it < 32; ++it) {
    int e = (it * 256 + tid) * 8;
    int r = e >> 11;                       // local row: gate = r>>3, i = r&7
    int k = e & 2047;
    const float* src = W + (((size_t)layer * 4 + (r >> 3)) * HH + (h0 + (r & 7))) * (size_t)KTOT + k;
    int slot = ((r >> 4) << 12) + (((k >> 8) * 8 + ((k >> 5) & 7)) << 6) + (r & 15) + (((k >> 3) & 3) << 4);
    *(us8*)&wlds[(unsigned)slot * 8] = pack8(*(const f4*)src, *(const f4*)(src + 4));
  }
  if (tid < 32) bias[tid] = Bb[((size_t)layer * 4 + (tid >> 3)) * HH + h0 + (tid & 7)];
  __syncthreads();

  const int lane = tid & 63;
  const int wid  = tid >> 6;
  const int nh = wid >> 1, jh = wid & 1;
  const int arow  = nh * 16 + (lane & 15);     // batch row for A fragments
  const int rbase = (lane >> 4) * 8;           // k-slice within 32-wide K step
  const unsigned short* wbase = &wlds[((unsigned)(jh * 4096 + lane)) * 8u];

  float lng = 0.f;                             // cell state (n=tid>>3, h=h0+(tid&7))

  // ---- shared epilogue: scatter gates, update state, write-through store, release ----
  auto epi = [&](int t, f4 acc) {
    int grow = nh * 16 + ((lane >> 4) << 2);
    int gcol = jh * 16 + (lane & 15);
    glds[(grow + 0) * 36 + gcol] = acc[0];
    glds[(grow + 1) * 36 + gcol] = acc[1];
    glds[(grow + 2) * 36 + gcol] = acc[2];
    glds[(grow + 3) * 36 + gcol] = acc[3];
    __syncthreads();
    {
      int n = tid >> 3, i = tid & 7;
      float gf = glds[n * 36 +  0 + i] + bias[ 0 + i];
      float gi = glds[n * 36 +  8 + i] + bias[ 8 + i];
      float go = glds[n * 36 + 16 + i] + bias[16 + i];
      float gc = glds[n * 36 + 24 + i] + bias[24 + i];
      float fg = 1.f / (1.f + __expf(-gf));
      float ig = 1.f / (1.f + __expf(-gi));
      float og = 1.f / (1.f + __expf(-go));
      lng = fg * lng + ig * gc;                   // cand raw (matches reference)
      float a  = fabsf(lng);
      float e  = __expf(-2.f * a);
      float th = __builtin_copysignf((1.f - e) / (1.f + e), lng);
      float sh = og * th;
      unsigned v16 = f2bf(sh);
      unsigned nb  = __shfl_down(v16, 1);
      unsigned pair = v16 | (nb << 16);
      if (layer == 0) {
        if (!(i & 1))
          stwt((unsigned*)(s1 + ((size_t)t * NB + n) * HH + h0 + i), pair);
      } else {
        stwt((unsigned*)(out + ((size_t)n * LL + t) * HH + h0 + i),
             __builtin_bit_cast(unsigned, sh));
        if (s2 && !(i & 1))
          stwt((unsigned*)(s2 + ((size_t)t * NB + n) * HH + h0 + i), pair);
      }
    }
    __syncthreads();   // vmcnt(0) per wave: all write-through stores at MALL
    if (tid == 0)
      __hip_atomic_fetch_add(mycnt + (size_t)t * 128 + mysub, 1u,
                             __ATOMIC_RELEASE, __HIP_MEMORY_SCOPE_AGENT);
  };

  if (layer == 0) {
    // nf(t): from x0 (flag-free). Computed AFTER release(t-1), inside the
    // wait window for cnt1[t-1]; only acc (16B) lives across the wait.
    auto nfAcc = [&](int t) {
      f4 a = {0.f, 0.f, 0.f, 0.f};
      if (x0) {
        const unsigned short* nsrc = x0 + ((size_t)t * NB + arow) * HH + rbase;
        #pragma unroll
        for (int c = 0; c < 4; ++c)
          #pragma unroll
          for (int m = 0; m < 8; ++m)
            a = MFMA(*(const us8*)(nsrc + c * 256 + m * 32),
                     *(const us8*)(wbase + ((4 + c) * 8 + m) * 512), a);
      } else {
        const float* nsrc = emb + (size_t)tokens[arow * LL + t] * HH + rbase;
        #pragma unroll
        for (int c = 0; c < 4; ++c)
          #pragma unroll
          for (int m = 0; m < 8; ++m)
            a = MFMA(pack8(*(const f4*)(nsrc + c * 256 + m * 32),
                           *(const f4*)(nsrc + c * 256 + m * 32 + 4)),
                     *(const us8*)(wbase + ((4 + c) * 8 + m) * 512), a);
      }
      return a;
    };

    f4 acc = nfAcc(0);
    for (int t = 0; t < LL; ++t) {
      if (t > 0) {
        waitsubs(cnt1 + (size_t)(t - 1) * 128, 16);     // discover peers' s1[t-1]
        const unsigned short* rsrc = s1 + ((size_t)(t - 1) * NB + arow) * HH + rbase;
        #pragma unroll
        for (int c = 0; c < 4; ++c)
          #pragma unroll
          for (int m = 0; m < 8; ++m)
            acc = MFMA(*(const us8*)(rsrc + c * 256 + m * 32),
                       *(const us8*)(wbase + (c * 8 + m) * 512), acc);
      }
      epi(t, acc);
      if (t + 1 < LL) acc = nfAcc(t + 1);               // off-chain, hidden in wait
    }
  } else {
    f4 acc = {0.f, 0.f, 0.f, 0.f};                      // rf(0) = 0
    for (int t = 0; t < LL; ++t) {
      waitsubs(cnt1 + (size_t)t * 128, 16);             // the only fresh wait
      {
        const unsigned short* nsrc = s1 + ((size_t)t * NB + arow) * HH + rbase;
        #pragma unroll
        for (int c = 0; c < 4; ++c)
          #pragma unroll
          for (int m = 0; m < 8; ++m)
            acc = MFMA(*(const us8*)(nsrc + c * 256 + m * 32),
                       *(const us8*)(wbase + ((4 + c) * 8 + m) * 512), acc);
      }
      epi(t, acc);
      if (t + 1 < LL) {
        // rf(t+1) from s2[t]: own-layer flag released just now by peers ->
        // near-instant discover; runs while layer-0 produces s1[t+1].
        waitsubs(cnt2 + (size_t)t * 128, 16);
        acc = f4{0.f, 0.f, 0.f, 0.f};
        if (s2) {
          const unsigned short* rsrc = s2 + ((size_t)t * NB + arow) * HH + rbase;
          #pragma unroll
          for (int c = 0; c < 4; ++c)
            #pragma unroll
            for (int m = 0; m < 8; ++m)
              acc = MFMA(*(const us8*)(rsrc + c * 256 + m * 32),
                         *(const us8*)(wbase + (c * 8 + m) * 512), acc);
        } else {
          const float* rsrc = out + ((size_t)arow * LL + t) * HH + rbase;
          #pragma unroll
          for (int c = 0; c < 4; ++c)
            #pragma unroll
            for (int m = 0; m < 8; ++m)
              acc = MFMA(pack8(*(const f4*)(rsrc + c * 256 + m * 32),
                               *(const f4*)(rsrc + c * 256 + m * 32 + 4)),
                         *(const us8*)(wbase + (c * 8 + m) * 512), acc);
        }
      }
    }
  }
}

extern "C" void kernel_launch(void* const* d_in, const int* in_sizes, int n_in,
                              void* d_out, int out_size, void* d_ws, size_t ws_size,
                              hipStream_t stream) {
  const int*   tokens = (const int*)d_in[0];
  const float* emb    = (const float*)d_in[1];
  const float* W      = (const float*)d_in[2];
  const float* Bb     = (const float*)d_in[3];
  float*       out    = (float*)d_out;

  // ws layout (R9):
  //   [0, 512KB)    sub-counters: cnt[2][512][8] on separate 64B lines
  //   [512KB,+32MB) s1 bf16 [512][32][1024]                    (required)
  //   optional s2 (layer-1 bf16 state), optional x0 (prepacked emb)
  const size_t FL = 524288;
  const size_t SZ = (size_t)LL * NB * HH * sizeof(unsigned short);   // 32 MiB
  unsigned*       flags = (unsigned*)d_ws;
  unsigned short* s1    = (unsigned short*)((char*)d_ws + FL);
  unsigned short* s2    = (ws_size >= FL + 2 * SZ) ? (unsigned short*)((char*)d_ws + FL + SZ) : nullptr;
  unsigned short* x0    = (ws_size >= FL + 3 * SZ) ? (unsigned short*)((char*)d_ws + FL + 2 * SZ) : nullptr;

  hipMemsetAsync(d_ws, 0, FL, stream);   // zero counters every replay (graph-captured)
  if (x0) prepack<<<dim3(8192), dim3(256), 0, stream>>>(tokens, emb, x0);

  void* args[] = { (void*)&tokens, (void*)&emb, (void*)&W, (void*)&Bb,
                   (void*)&out, (void*)&flags, (void*)&s1, (void*)&s2, (void*)&x0 };
  hipLaunchCooperativeKernel((void*)lstm_persist, dim3(256), dim3(256), args, 0, stream);
}